// Round 16
// baseline (425.337 us; speedup 1.0000x reference)
//
#include <hip/hip_runtime.h>
#include <hip/hip_bf16.h>
#include <cstdint>

#define S_LEN 1024
#define HID   4096
#define NH    32
#define NKV   8
#define HD    128
#define NLOW  3968      // HID - SEL (= 248*16)
#define M_ROWS 2048     // B*S
#define NQKV  6144      // (NH+2*NKV)*HD

typedef _Float16 f16_t;
typedef _Float16 f16x8 __attribute__((ext_vector_type(8)));
typedef float    f32x4 __attribute__((ext_vector_type(4)));
typedef float    f32x16 __attribute__((ext_vector_type(16)));

#define MFMA16(a,b,c) __builtin_amdgcn_mfma_f32_16x16x32_f16(a,b,c,0,0,0)
#define MFMA32(a,b,c) __builtin_amdgcn_mfma_f32_32x32x16_f16(a,b,c,0,0,0)

__device__ inline void gload16(const void* g, void* l) {
  __builtin_amdgcn_global_load_lds(
      (const __attribute__((address_space(1))) void*)g,
      (__attribute__((address_space(3))) void*)l, 16, 0, 0);
}

#define WAITV(n) asm volatile("s_waitcnt vmcnt(" #n ")" ::: "memory")
#define LGKM0()  asm volatile("s_waitcnt lgkmcnt(0)" ::: "memory")
#define FENCE()  asm volatile("" ::: "memory")

// ---------- wave reductions (64-wide) ----------
__device__ inline float wred_max(float v){ for(int o=32;o;o>>=1) v=fmaxf(v,__shfl_xor(v,o)); return v; }
__device__ inline float wred_min(float v){ for(int o=32;o;o>>=1) v=fminf(v,__shfl_xor(v,o)); return v; }
__device__ inline float wred_sum(float v){ for(int o=32;o;o>>=1) v+=__shfl_xor(v,o); return v; }

// ---------- 1. activation permute + per-row int8 quant ----------
__global__ __launch_bounds__(256) void aquant_kernel(const float* __restrict__ X,
                                                     const int* __restrict__ reorder,
                                                     f16_t* __restrict__ out,
                                                     float* __restrict__ sarr)
{
  __shared__ float xs[HID];
  __shared__ float red[4];
  int row = blockIdx.x;
  int t = threadIdx.x;
  const f32x4* xr4 = (const f32x4*)(X + (size_t)row * HID);
  f32x4* xs4 = (f32x4*)xs;
  #pragma unroll
  for (int i = 0; i < 4; i++)
    xs4[t + i * 256] = xr4[t + i * 256];
  __syncthreads();

  int c0 = t * 16;                 // NLOW % 16 == 0: each thread all-low or all-keep
  float v[16];
  #pragma unroll
  for (int j = 0; j < 16; j++)
    v[j] = xs[reorder[c0 + j]];

  float amax = 0.f;
  if (c0 < NLOW) {
    #pragma unroll
    for (int j = 0; j < 16; j++) amax = fmaxf(amax, fabsf(v[j]));
  }
  amax = wred_max(amax);
  if ((t & 63) == 0) red[t >> 6] = amax;
  __syncthreads();
  float scale = fmaxf(fmaxf(fmaxf(red[0], red[1]), fmaxf(red[2], red[3])), 1e-5f) / 127.0f;
  if (t == 0) sarr[row] = scale;

  f16_t* orow = out + (size_t)row * HID;
  f16x8 o0, o1;
  if (c0 < NLOW) {
    #pragma unroll
    for (int j = 0; j < 8; j++) {
      o0[j] = (f16_t)fminf(fmaxf(rintf(v[j] / scale), -128.f), 127.f);
      o1[j] = (f16_t)fminf(fmaxf(rintf(v[j + 8] / scale), -128.f), 127.f);
    }
  } else {
    #pragma unroll
    for (int j = 0; j < 8; j++) { o0[j] = (f16_t)(v[j] / scale); o1[j] = (f16_t)(v[j + 8] / scale); }
  }
  *(f16x8*)(orow + c0) = o0;
  *(f16x8*)(orow + c0 + 8) = o1;
}

// ---------- 2. weight permute + per-group 4-bit asym quant -> f16 ----------
__device__ inline void wquant_body(const float* __restrict__ wrowbase,
                                   const int* __restrict__ reorder,
                                   f16_t* __restrict__ orow, int t, float* xs)
{
  const f32x4* wrow4 = (const f32x4*)wrowbase;
  f32x4* xs4 = (f32x4*)xs;
  #pragma unroll
  for (int i = 0; i < 4; i++)
    xs4[t + i * 256] = wrow4[t + i * 256];
  __syncthreads();

  int c0 = t * 16;
  float v[16];
  #pragma unroll
  for (int j = 0; j < 16; j++)
    v[j] = xs[reorder[c0 + j]];

  f16x8 o0, o1;
  if (c0 < NLOW) {
    float mn = v[0], mx = v[0];
    #pragma unroll
    for (int j = 1; j < 16; j++) { mn = fminf(mn, v[j]); mx = fmaxf(mx, v[j]); }
    #pragma unroll
    for (int o = 1; o <= 4; o <<= 1) {
      mn = fminf(mn, __shfl_xor(mn, o));
      mx = fmaxf(mx, __shfl_xor(mx, o));
    }
    float scale = fmaxf(mx - mn, 1e-5f) / 15.0f;
    float base = fminf(fmaxf(rintf(-mn / scale), 0.f), 15.f);
    #pragma unroll
    for (int j = 0; j < 8; j++) {
      o0[j] = (f16_t)((fminf(fmaxf(rintf(v[j] / scale) + base, 0.f), 15.f) - base) * scale);
      o1[j] = (f16_t)((fminf(fmaxf(rintf(v[j + 8] / scale) + base, 0.f), 15.f) - base) * scale);
    }
  } else {
    #pragma unroll
    for (int j = 0; j < 8; j++) { o0[j] = (f16_t)v[j]; o1[j] = (f16_t)v[j + 8]; }
  }
  *(f16x8*)(orow + c0) = o0;
  *(f16x8*)(orow + c0 + 8) = o1;
}

// all four weight matrices in one launch
__global__ __launch_bounds__(256) void wquant_all(const float* __restrict__ Wq,
                                                  const float* __restrict__ Wk,
                                                  const float* __restrict__ Wv,
                                                  const float* __restrict__ Wo,
                                                  const int* __restrict__ r_qkv,
                                                  const int* __restrict__ r_o,
                                                  f16_t* __restrict__ wcat,
                                                  f16_t* __restrict__ woq)
{
  __shared__ float xs[HID];
  int row = blockIdx.x;
  const float* src; const int* reo; f16_t* dst;
  if (row < 4096)      { src = Wq + (size_t)row * HID;          reo = r_qkv; dst = wcat + (size_t)row * HID; }
  else if (row < 5120) { src = Wk + (size_t)(row - 4096) * HID; reo = r_qkv; dst = wcat + (size_t)row * HID; }
  else if (row < 6144) { src = Wv + (size_t)(row - 5120) * HID; reo = r_qkv; dst = wcat + (size_t)row * HID; }
  else                 { src = Wo + (size_t)(row - 6144) * HID; reo = r_o;   dst = woq + (size_t)(row - 6144) * HID; }
  wquant_body(src, reo, dst, threadIdx.x, xs);
}

// ---------- 3. f16 MFMA GEMM, 32x32x16, FRAGMENT-ORDER LDS (zero conflicts) ----------
// C[M,N] = rowscale[m]*(A[M,K]*B[N,K]^T). 8 waves as 4M x 2N, BK=64 dbuf.
// LDS in MFMA-fragment order: chunk (rowgroup, ks) is 1KB, lane-linear 16B slots.
// Lane l's slot holds row = group*32 + (l&31), cols ks*16 + (l>>5)*8 .. +8 —
// exactly the 32x32x16 A/B per-lane operand mapping (verified in round 14).
// All ds_read_b128 are wave-uniform-base + lane*16 -> linear, conflict-free.
template<int BM_, int BN_, typename OT>
__global__ __launch_bounds__(512, 4) void gemm_bt32(const f16_t* __restrict__ A,
                                                    const f16_t* __restrict__ Bm,
                                                    OT* __restrict__ C,
                                                    const float* __restrict__ rowscale,
                                                    int N, int K)
{
  constexpr int NSPAN = BN_ / 2;        // per-wave N span
  constexpr int NR    = NSPAN / 32;     // 32x32 frags per wave (3 for 192, 2 for 128)
  constexpr int ACH   = (BM_ / 32) * 4; // A chunks = rowgroups x 4 ks
  constexpr int TCH   = ACH + (BN_ / 32) * 4;
  constexpr int CPW   = TCH / 8;        // chunks per wave (5 for 128x192, 4 for 128x128)
  static_assert(TCH % 8 == 0 && BM_ % 32 == 0 && BN_ % 64 == 0, "geometry");
  __shared__ f16_t As[2][BM_ * 64];
  __shared__ f16_t Bs[2][BN_ * 64];

  int tid = threadIdx.x;
  int w = tid >> 6, lane = tid & 63;
  int l31 = lane & 31, g5 = lane >> 5;
  int wm = w >> 1, wn = w & 1;          // 4M x 2N
  int gm0 = blockIdx.y * BM_, gn0 = blockIdx.x * BN_;
  int NT = K >> 6;
  int lr = lane & 31, lc8 = (lane >> 5) * 8;  // staging = fragment mapping (FIXED)

  f32x16 acc[NR];
  #pragma unroll
  for (int n = 0; n < NR; n++)
    #pragma unroll
    for (int j = 0; j < 16; j++) acc[n][j] = 0.f;

  auto STAGE = [&](int t, int s) {
    #pragma unroll
    for (int i = 0; i < CPW; i++) {
      int ch = w + 8 * i;               // wave-uniform chunk id
      if (ch < ACH) {
        int r = gm0 + (ch >> 2) * 32 + lr;
        gload16(A + (size_t)r * K + t * 64 + (ch & 3) * 16 + lc8, &As[s][ch * 512]);
      } else {
        int cb = ch - ACH;
        int r = gn0 + (cb >> 2) * 32 + lr;
        gload16(Bm + (size_t)r * K + t * 64 + (cb & 3) * 16 + lc8, &Bs[s][cb * 512]);
      }
    }
  };

  STAGE(0, 0);
  for (int t = 0; t < NT; t++) {
    int cur = t & 1;
    if (t + 1 < NT) {
      STAGE(t + 1, cur ^ 1);
      if constexpr (CPW == 5) { WAITV(5); } else { WAITV(4); }
    } else {
      WAITV(0);
    }
    FENCE();
    __builtin_amdgcn_s_barrier();       // buf[cur] staged & visible
    FENCE();

    f16x8 af[4];
    #pragma unroll
    for (int ks = 0; ks < 4; ks++)
      af[ks] = *(const f16x8*)(&As[cur][(wm * 4 + ks) * 512 + lane * 8]);
    __builtin_amdgcn_s_setprio(1);
    #pragma unroll
    for (int n = 0; n < NR; n++) {
      int bg = wn * NR + n;
      #pragma unroll
      for (int ks = 0; ks < 4; ks++) {
        f16x8 bf = *(const f16x8*)(&Bs[cur][(bg * 4 + ks) * 512 + lane * 8]);
        acc[n] = MFMA32(af[ks], bf, acc[n]);
      }
    }
    __builtin_amdgcn_s_setprio(0);
    LGKM0();
    __builtin_amdgcn_s_barrier();       // all reads of buf[cur] done
    FENCE();
  }

  #pragma unroll
  for (int reg = 0; reg < 16; reg++) {
    int grow = gm0 + wm * 32 + (reg & 3) + 8 * (reg >> 2) + 4 * g5;
    float sc = rowscale[grow];
    #pragma unroll
    for (int n = 0; n < NR; n++) {
      int gcol = gn0 + wn * NSPAN + n * 32 + l31;
      C[(size_t)grow * N + gcol] = (OT)(acc[n][reg] * sc);
    }
  }
}

// ---------- 4. post: RMSNorm / RoPE for Q,K (V handled by vtrans) ----------
__global__ __launch_bounds__(512) void post_kernel(const f16_t* __restrict__ qkv,
                                                   const float* __restrict__ cosb,
                                                   const float* __restrict__ sinb,
                                                   const float* __restrict__ qnw,
                                                   const float* __restrict__ knw,
                                                   f16_t* __restrict__ Q,
                                                   f16_t* __restrict__ K)
{
  int m = blockIdx.x;
  int b = m >> 10, s = m & 1023;
  int tid = threadIdx.x;
  int w = tid >> 6, l = tid & 63;

  float c0 = cosb[(size_t)m * HD + l];
  float c1 = cosb[(size_t)m * HD + 64 + l];
  float s0 = sinb[(size_t)m * HD + l];
  float s1 = sinb[(size_t)m * HD + 64 + l];
  float qw0 = qnw[l], qw1 = qnw[64 + l];
  float kw0 = knw[l], kw1 = knw[64 + l];
  const f16_t* row = qkv + (size_t)m * NQKV;

  #pragma unroll
  for (int it = 0; it < 5; it++) {
    int slot = it * 8 + w;
    const f16_t* hp = row + slot * HD;
    float x0 = (float)hp[l];
    float x1 = (float)hp[l + 64];
    if (slot < NH) {                       // q: norm -> rope -> *1/sqrt(HD)
      int h = slot;
      float ss = wred_sum(x0 * x0 + x1 * x1);
      float r = 1.0f / sqrtf(ss * (1.0f / 128.0f) + 1e-6f);
      float xn0 = x0 * r * qw0, xn1 = x1 * r * qw1;
      float o0 = (xn0 * c0 - xn1 * s0) * 0.08838834764831845f;
      float o1 = (xn1 * c1 + xn0 * s1) * 0.08838834764831845f;
      f16_t* qp = Q + (((size_t)(b * NH + h)) * S_LEN + s) * HD;
      qp[l] = (f16_t)o0;
      qp[l + 64] = (f16_t)o1;
    } else {                               // k: norm -> quant -> rope
      int h = slot - NH;
      float ss = wred_sum(x0 * x0 + x1 * x1);
      float r = 1.0f / sqrtf(ss * (1.0f / 128.0f) + 1e-6f);
      float xn0 = x0 * r * kw0, xn1 = x1 * r * kw1;
      float mn = wred_min(fminf(xn0, xn1));
      float mx = wred_max(fmaxf(xn0, xn1));
      float scale = fmaxf(mx - mn, 1e-5f) / 15.0f;
      float base = fminf(fmaxf(rintf(-mn / scale), 0.f), 15.f);
      float q0 = (fminf(fmaxf(rintf(xn0 / scale) + base, 0.f), 15.f) - base) * scale;
      float q1 = (fminf(fmaxf(rintf(xn1 / scale) + base, 0.f), 15.f) - base) * scale;
      float o0 = q0 * c0 - q1 * s0;
      float o1 = q1 * c1 + q0 * s1;
      f16_t* kp = K + (((size_t)(b * NKV + h)) * S_LEN + s) * HD;
      kp[l] = (f16_t)o0;
      kp[l + 64] = (f16_t)o1;
    }
  }
}

// ---------- 4b. V: quantize + transpose via LDS (coalesced Vt writes) ----------
__global__ __launch_bounds__(256) void vtrans_kernel(const f16_t* __restrict__ qkv,
                                                     f16_t* __restrict__ Vt)
{
  __shared__ f16_t vs[128][129];   // +1 pad: column reads spread banks
  int blk = blockIdx.x;
  int st = blk & 7;                // s-tile
  int bh = blk >> 3;               // b*NKV + h
  int b = bh >> 3, h = bh & 7;
  int s0 = st * 128;
  int t = threadIdx.x;

  int r = t >> 1, hf = t & 1;
  const f16_t* src = qkv + ((size_t)(b * S_LEN + s0 + r)) * NQKV + (NH + NKV + h) * HD + hf * 64;
  #pragma unroll
  for (int i = 0; i < 8; i++)
    *(f16x8*)(&vs[r][hf * 64 + i * 8]) = *(const f16x8*)(src + i * 8);
  __syncthreads();

  float mn = 1e30f, mx = -1e30f;
  #pragma unroll
  for (int i = 0; i < 64; i++) {
    float x = (float)vs[r][hf * 64 + i];
    mn = fminf(mn, x); mx = fmaxf(mx, x);
  }
  mn = fminf(mn, __shfl_xor(mn, 1));
  mx = fmaxf(mx, __shfl_xor(mx, 1));
  float scale = fmaxf(mx - mn, 1e-5f) / 15.0f;
  float base = fminf(fmaxf(rintf(-mn / scale), 0.f), 15.f);
  #pragma unroll
  for (int i = 0; i < 64; i++) {
    int d = hf * 64 + i;
    float x = (float)vs[r][d];
    vs[r][d] = (f16_t)((fminf(fmaxf(rintf(x / scale) + base, 0.f), 15.f) - base) * scale);
  }
  __syncthreads();

  int wv = t >> 6, ln = t & 63;
  #pragma unroll
  for (int dd = 0; dd < 32; dd++) {
    int d = wv * 32 + dd;
    f16_t* orow = Vt + ((size_t)bh * HD + d) * S_LEN + s0;
    orow[ln] = vs[ln][d];
    orow[64 + ln] = vs[64 + ln][d];
  }
}

// ---------- 5. flash attention, f16 MFMA, 8 waves / 128 q-rows, dbuf K/V ----------
__global__ __launch_bounds__(512) void attn_mfma(const f16_t* __restrict__ Q,
                                                 const f16_t* __restrict__ Kg,
                                                 const f16_t* __restrict__ Vg,
                                                 float* __restrict__ O)
{
  __shared__ f16_t Ks[2][64 * 128];
  __shared__ f16_t Vs[2][128 * 64];
  __shared__ f16_t Ps[8 * 16 * 64];
  int tid = threadIdx.x;
  int w = tid >> 6, lane = tid & 63;
  int g = lane >> 4, l15 = lane & 15;
  int i = blockIdx.x;
  int base = i & 255, half = i >> 8;
  int bh = base & 63;
  int b = bh >> 5, h = bh & 31;
  int qbase = base >> 6;                 // 0..3
  int qb = half ? 7 - qbase : qbase;     // complementary pairing
  int kvh = h >> 2;
  int q0 = qb * 128;

  const f16_t* Qp = Q + (size_t)(b * NH + h) * S_LEN * HD;
  const f16_t* Kp = Kg + (size_t)(b * NKV + kvh) * S_LEN * HD;
  const f16_t* Vp = Vg + (size_t)(b * NKV + kvh) * HD * S_LEN;

  int qrow = q0 + w * 16 + l15;
  int myqmax = q0 + w * 16 + 15;
  f16x8 qf[4];
  #pragma unroll
  for (int c = 0; c < 4; c++)
    qf[c] = *(const f16x8*)(Qp + (size_t)qrow * HD + c * 32 + g * 8);

  f32x4 zf = {0.f, 0.f, 0.f, 0.f};
  f32x4 oacc[8];
  #pragma unroll
  for (int nd = 0; nd < 8; nd++) oacc[nd] = zf;
  float mrun[4], lrun[4];
  #pragma unroll
  for (int j = 0; j < 4; j++) { mrun[j] = -INFINITY; lrun[j] = 0.f; }

  int vrow = lane >> 3, vslot = lane & 7;
  auto STAGEKV = [&](int it, int bb) {
    int kt = it * 64;
    #pragma unroll
    for (int ii = 0; ii < 2; ii++) {
      int c = w + 8 * ii;
      int row = c * 4 + g;
      gload16(Kp + (size_t)(kt + row) * HD + (l15 ^ (row & 7)) * 8, &Ks[bb][c * 512]);
    }
    #pragma unroll
    for (int ii = 0; ii < 2; ii++) {
      int c = w + 8 * ii;
      int row = c * 8 + vrow;
      gload16(Vp + (size_t)row * S_LEN + kt + (vslot ^ (row & 7)) * 8, &Vs[bb][c * 512]);
    }
  };

  f16_t* pw = Ps + w * 1024;
  int ntiles = 2 * qb + 2;
  STAGEKV(0, 0);
  for (int it = 0; it < ntiles; it++) {
    int cur = it & 1;
    if (it + 1 < ntiles) {
      STAGEKV(it + 1, cur ^ 1);
      WAITV(4);
    } else {
      WAITV(0);
    }
    FENCE();
    __builtin_amdgcn_s_barrier();
    FENCE();

    int kt = it * 64;
    if (kt <= myqmax) {
      // QK^T: S[16q][64k]
      f32x4 sv[4];
      #pragma unroll
      for (int nk = 0; nk < 4; nk++) sv[nk] = zf;
      __builtin_amdgcn_s_setprio(1);
      #pragma unroll
      for (int nk = 0; nk < 4; nk++) {
        int krow = nk * 16 + l15;
        #pragma unroll
        for (int c = 0; c < 4; c++) {
          f16x8 kf = *(const f16x8*)(&Ks[cur][krow * 128 + (((c * 4 + g) ^ (krow & 7)) * 8)]);
          sv[nk] = MFMA16(qf[c], kf, sv[nk]);
        }
      }
      __builtin_amdgcn_s_setprio(0);
      // causal mask
      #pragma unroll
      for (int nk = 0; nk < 4; nk++) {
        int kcol = kt + nk * 16 + l15;
        #pragma unroll
        for (int j = 0; j < 4; j++) {
          int qr = q0 + w * 16 + g * 4 + j;
          if (kcol > qr) sv[nk][j] = -1e30f;
        }
      }
      // online softmax
      float alpha[4];
      #pragma unroll
      for (int j = 0; j < 4; j++) {
        float mr = fmaxf(fmaxf(sv[0][j], sv[1][j]), fmaxf(sv[2][j], sv[3][j]));
        mr = fmaxf(mr, __shfl_xor(mr, 1));
        mr = fmaxf(mr, __shfl_xor(mr, 2));
        mr = fmaxf(mr, __shfl_xor(mr, 4));
        mr = fmaxf(mr, __shfl_xor(mr, 8));
        float mnew = fmaxf(mrun[j], mr);
        alpha[j] = __expf(mrun[j] - mnew);
        float lt = 0.f;
        #pragma unroll
        for (int nk = 0; nk < 4; nk++) {
          float p = __expf(sv[nk][j] - mnew);
          sv[nk][j] = p;
          lt += p;
        }
        lt += __shfl_xor(lt, 1);
        lt += __shfl_xor(lt, 2);
        lt += __shfl_xor(lt, 4);
        lt += __shfl_xor(lt, 8);
        lrun[j] = lrun[j] * alpha[j] + lt;
        mrun[j] = mnew;
      }
      // write P (f16, swizzled rows of 64 elems)
      #pragma unroll
      for (int j = 0; j < 4; j++) {
        int ql = g * 4 + j;
        #pragma unroll
        for (int nk = 0; nk < 4; nk++) {
          int kl = nk * 16 + l15;
          int ss = (kl >> 3) ^ (ql & 7);
          pw[ql * 64 + ss * 8 + (kl & 7)] = (f16_t)sv[nk][j];
        }
      }
      // rescale O
      #pragma unroll
      for (int nd = 0; nd < 8; nd++)
        #pragma unroll
        for (int j = 0; j < 4; j++) oacc[nd][j] *= alpha[j];
      // PV: O[16q][128d] += P[16q][64k] * V[64k][128d]
      __builtin_amdgcn_s_setprio(1);
      #pragma unroll
      for (int kc = 0; kc < 2; kc++) {
        f16x8 pf = *(const f16x8*)(pw + l15 * 64 + ((kc * 4 + g) ^ (l15 & 7)) * 8);
        #pragma unroll
        for (int nd = 0; nd < 8; nd++) {
          int d = nd * 16 + l15;
          f16x8 vf = *(const f16x8*)(&Vs[cur][d * 64 + (((kc * 4 + g) ^ (d & 7)) * 8)]);
          oacc[nd] = MFMA16(pf, vf, oacc[nd]);
        }
      }
      __builtin_amdgcn_s_setprio(0);
      LGKM0();
    }
    __builtin_amdgcn_s_barrier();
    FENCE();
  }
  // epilogue: write (B,S,NH*HD) f32
  #pragma unroll
  for (int j = 0; j < 4; j++) {
    float invl = 1.0f / lrun[j];
    float* orow = O + ((size_t)(b * S_LEN) + q0 + w * 16 + g * 4 + j) * (NH * HD) + h * HD + l15;
    #pragma unroll
    for (int nd = 0; nd < 8; nd++) orow[nd * 16] = oacc[nd][j] * invl;
  }
}

// ---------- launcher ----------
extern "C" void kernel_launch(void* const* d_in, const int* in_sizes, int n_in,
                              void* d_out, int out_size, void* d_ws, size_t ws_size,
                              hipStream_t stream) {
  const float* hidden = (const float*)d_in[0];
  const float* cosb   = (const float*)d_in[1];
  const float* sinb   = (const float*)d_in[2];
  const float* Wq     = (const float*)d_in[3];
  const float* Wk     = (const float*)d_in[4];
  const float* Wv     = (const float*)d_in[5];
  const float* Wo     = (const float*)d_in[6];
  const float* qnw    = (const float*)d_in[7];
  const float* knw    = (const float*)d_in[8];
  const int*   r_qkv  = (const int*)d_in[9];
  const int*   r_o    = (const int*)d_in[10];
  float* out = (float*)d_out;

  f16_t* xq   = (f16_t*)d_ws;                                    // [2048][4096] f16
  f16_t* wcat = xq + (size_t)M_ROWS * HID;                       // [6144][4096] f16
  f16_t* woq  = wcat + (size_t)NQKV * HID;                       // [4096][4096] f16
  f16_t* qkv  = woq + (size_t)HID * HID;                         // [2048][6144] f16
  f16_t* Qb   = qkv + (size_t)M_ROWS * NQKV;                     // [2*32*1024][128] f16
  f16_t* Kb   = Qb + (size_t)2 * NH * S_LEN * HD;                // [2*8*1024][128] f16
  f16_t* Vt   = Kb + (size_t)2 * NKV * S_LEN * HD;               // [2*8][128][1024] f16
  float* sa1  = (float*)(Vt + (size_t)2 * NKV * S_LEN * HD);     // [2048] f32
  float* sa2  = sa1 + M_ROWS;                                    // [2048] f32
  float* ao   = sa2 + M_ROWS;                                    // [2048][4096] f32
  size_t needed = (size_t)((char*)(ao + (size_t)M_ROWS * HID) - (char*)d_ws);
  if (ws_size < needed) return;
  f16_t* oq = xq;      // alias: quantized attn output (xq dead after QKV GEMM)

  aquant_kernel<<<M_ROWS, 256, 0, stream>>>(hidden, r_qkv, xq, sa1);
  wquant_all<<<NQKV + HID, 256, 0, stream>>>(Wq, Wk, Wv, Wo, r_qkv, r_o, wcat, woq);
  // QKV: 128x192 tiles (LDS 80KB -> 2 blocks/CU), 32x32x16 MFMA fragment-order LDS
  gemm_bt32<128, 192, f16_t><<<dim3(NQKV / 192, M_ROWS / 128), 512, 0, stream>>>(xq, wcat, qkv, sa1, NQKV, HID);
  post_kernel<<<M_ROWS, 512, 0, stream>>>(qkv, cosb, sinb, qnw, knw, Qb, Kb);
  vtrans_kernel<<<2 * NKV * 8, 256, 0, stream>>>(qkv, Vt);
  attn_mfma<<<512, 512, 0, stream>>>(Qb, Kb, Vt, ao);
  aquant_kernel<<<M_ROWS, 256, 0, stream>>>(ao, r_o, oq, sa2);
  // O-proj: 128x128 tiles (LDS 64KB -> 2 blocks/CU), 32x32x16 MFMA fragment-order LDS
  gemm_bt32<128, 128, float><<<dim3(HID / 128, M_ROWS / 128), 512, 0, stream>>>(oq, woq, out, sa2, HID, HID);
}

// Round 17
// 297.058 us; speedup vs baseline: 1.4318x; 1.4318x over previous
//
#include <hip/hip_runtime.h>
#include <hip/hip_bf16.h>
#include <cstdint>

#define S_LEN 1024
#define HID   4096
#define NH    32
#define NKV   8
#define HD    128
#define NLOW  3968      // HID - SEL (= 248*16)
#define M_ROWS 2048     // B*S
#define NQKV  6144      // (NH+2*NKV)*HD

typedef _Float16 f16_t;
typedef _Float16 f16x8 __attribute__((ext_vector_type(8)));
typedef float    f32x4 __attribute__((ext_vector_type(4)));

#define MFMA16(a,b,c) __builtin_amdgcn_mfma_f32_16x16x32_f16(a,b,c,0,0,0)

__device__ inline void gload16(const void* g, void* l) {
  __builtin_amdgcn_global_load_lds(
      (const __attribute__((address_space(1))) void*)g,
      (__attribute__((address_space(3))) void*)l, 16, 0, 0);
}

#define WAITV(n) asm volatile("s_waitcnt vmcnt(" #n ")" ::: "memory")
#define LGKM0()  asm volatile("s_waitcnt lgkmcnt(0)" ::: "memory")
#define FENCE()  asm volatile("" ::: "memory")

// ---------- wave reductions (64-wide) ----------
__device__ inline float wred_max(float v){ for(int o=32;o;o>>=1) v=fmaxf(v,__shfl_xor(v,o)); return v; }
__device__ inline float wred_min(float v){ for(int o=32;o;o>>=1) v=fminf(v,__shfl_xor(v,o)); return v; }
__device__ inline float wred_sum(float v){ for(int o=32;o;o>>=1) v+=__shfl_xor(v,o); return v; }

// ---------- 1. activation permute + per-row int8 quant (templated input) ----------
// Stage row in LDS coalesced, gather from LDS. low cols: INTEGER q (exact in f16);
// keep cols: v/scale. GEMM epilogue applies rowscale -> A-side numerically exact.
template<typename IT>
__global__ __launch_bounds__(256) void aquant_kernel(const IT* __restrict__ X,
                                                     const int* __restrict__ reorder,
                                                     f16_t* __restrict__ out,
                                                     float* __restrict__ sarr)
{
  __shared__ float xs[HID];
  __shared__ float red[4];
  int row = blockIdx.x;
  int t = threadIdx.x;
  if constexpr (sizeof(IT) == 4) {
    const f32x4* xr4 = (const f32x4*)(X + (size_t)row * HID);
    f32x4* xs4 = (f32x4*)xs;
    #pragma unroll
    for (int i = 0; i < 4; i++)
      xs4[t + i * 256] = xr4[t + i * 256];
  } else {
    const f16x8* xr8 = (const f16x8*)(X + (size_t)row * HID);
    #pragma unroll
    for (int i = 0; i < 2; i++) {
      f16x8 v8 = xr8[t + i * 256];
      #pragma unroll
      for (int j = 0; j < 8; j++)
        xs[(t + i * 256) * 8 + j] = (float)v8[j];
    }
  }
  __syncthreads();

  int c0 = t * 16;                 // NLOW % 16 == 0: each thread all-low or all-keep
  float v[16];
  #pragma unroll
  for (int j = 0; j < 16; j++)
    v[j] = xs[reorder[c0 + j]];

  float amax = 0.f;
  if (c0 < NLOW) {
    #pragma unroll
    for (int j = 0; j < 16; j++) amax = fmaxf(amax, fabsf(v[j]));
  }
  amax = wred_max(amax);
  if ((t & 63) == 0) red[t >> 6] = amax;
  __syncthreads();
  float scale = fmaxf(fmaxf(fmaxf(red[0], red[1]), fmaxf(red[2], red[3])), 1e-5f) / 127.0f;
  if (t == 0) sarr[row] = scale;

  f16_t* orow = out + (size_t)row * HID;
  f16x8 o0, o1;
  if (c0 < NLOW) {
    #pragma unroll
    for (int j = 0; j < 8; j++) {
      o0[j] = (f16_t)fminf(fmaxf(rintf(v[j] / scale), -128.f), 127.f);
      o1[j] = (f16_t)fminf(fmaxf(rintf(v[j + 8] / scale), -128.f), 127.f);
    }
  } else {
    #pragma unroll
    for (int j = 0; j < 8; j++) { o0[j] = (f16_t)(v[j] / scale); o1[j] = (f16_t)(v[j + 8] / scale); }
  }
  *(f16x8*)(orow + c0) = o0;
  *(f16x8*)(orow + c0 + 8) = o1;
}

// ---------- 2. weight permute + per-group 4-bit asym quant -> f16 ----------
__device__ inline void wquant_body(const float* __restrict__ wrowbase,
                                   const int* __restrict__ reorder,
                                   f16_t* __restrict__ orow, int t, float* xs)
{
  const f32x4* wrow4 = (const f32x4*)wrowbase;
  f32x4* xs4 = (f32x4*)xs;
  #pragma unroll
  for (int i = 0; i < 4; i++)
    xs4[t + i * 256] = wrow4[t + i * 256];
  __syncthreads();

  int c0 = t * 16;
  float v[16];
  #pragma unroll
  for (int j = 0; j < 16; j++)
    v[j] = xs[reorder[c0 + j]];

  f16x8 o0, o1;
  if (c0 < NLOW) {
    float mn = v[0], mx = v[0];
    #pragma unroll
    for (int j = 1; j < 16; j++) { mn = fminf(mn, v[j]); mx = fmaxf(mx, v[j]); }
    #pragma unroll
    for (int o = 1; o <= 4; o <<= 1) {
      mn = fminf(mn, __shfl_xor(mn, o));
      mx = fmaxf(mx, __shfl_xor(mx, o));
    }
    float scale = fmaxf(mx - mn, 1e-5f) / 15.0f;
    float base = fminf(fmaxf(rintf(-mn / scale), 0.f), 15.f);
    #pragma unroll
    for (int j = 0; j < 8; j++) {
      o0[j] = (f16_t)((fminf(fmaxf(rintf(v[j] / scale) + base, 0.f), 15.f) - base) * scale);
      o1[j] = (f16_t)((fminf(fmaxf(rintf(v[j + 8] / scale) + base, 0.f), 15.f) - base) * scale);
    }
  } else {
    #pragma unroll
    for (int j = 0; j < 8; j++) { o0[j] = (f16_t)v[j]; o1[j] = (f16_t)v[j + 8]; }
  }
  *(f16x8*)(orow + c0) = o0;
  *(f16x8*)(orow + c0 + 8) = o1;
}

// all four weight matrices in one launch
__global__ __launch_bounds__(256) void wquant_all(const float* __restrict__ Wq,
                                                  const float* __restrict__ Wk,
                                                  const float* __restrict__ Wv,
                                                  const float* __restrict__ Wo,
                                                  const int* __restrict__ r_qkv,
                                                  const int* __restrict__ r_o,
                                                  f16_t* __restrict__ wcat,
                                                  f16_t* __restrict__ woq)
{
  __shared__ float xs[HID];
  int row = blockIdx.x;
  const float* src; const int* reo; f16_t* dst;
  if (row < 4096)      { src = Wq + (size_t)row * HID;          reo = r_qkv; dst = wcat + (size_t)row * HID; }
  else if (row < 5120) { src = Wk + (size_t)(row - 4096) * HID; reo = r_qkv; dst = wcat + (size_t)row * HID; }
  else if (row < 6144) { src = Wv + (size_t)(row - 5120) * HID; reo = r_qkv; dst = wcat + (size_t)row * HID; }
  else                 { src = Wo + (size_t)(row - 6144) * HID; reo = r_o;   dst = woq + (size_t)(row - 6144) * HID; }
  wquant_body(src, reo, dst, threadIdx.x, xs);
}

// ---------- 3. f16 MFMA GEMM 16x16x32 (round-13 anchor: BK=64 dbuf, 2 blocks/CU) ----------
// LDS <= 80KB so two blocks co-reside per CU: cross-block overlap hides the
// per-block barrier drain (independent barriers). Swizzle slot ^= row&7 (2-way free).
template<int BM_, int BN_, int WM, typename OT>
__global__ __launch_bounds__(512, 4) void gemm_bt(const f16_t* __restrict__ A,
                                                  const f16_t* __restrict__ Bm,
                                                  OT* __restrict__ C,
                                                  const float* __restrict__ rowscale,
                                                  int N, int K)
{
  constexpr int WN   = 8 / WM;
  constexpr int MREP = BM_ / WM / 16;   // per-wave M fragments
  constexpr int NREP = BN_ / WN / 16;   // per-wave N fragments
  constexpr int ACH  = BM_ / 8;         // A chunks (1KB = 8 rows x 64 f16) per K-tile
  constexpr int TCH  = ACH + BN_ / 8;
  constexpr int CPW  = TCH / 8;         // chunks per wave
  static_assert(TCH % 8 == 0, "chunks must split evenly across 8 waves");
  __shared__ f16_t As[2][BM_ * 64];
  __shared__ f16_t Bs[2][BN_ * 64];

  int tid = threadIdx.x;
  int w = tid >> 6, lane = tid & 63;
  int g = lane >> 4, l15 = lane & 15;
  int wm = w / WN, wn = w % WN;
  int gm0 = blockIdx.y * BM_, gn0 = blockIdx.x * BN_;
  int NT = K >> 6;
  int srow = lane >> 3;                       // 0..7 row within chunk
  int sslot = (lane & 7) ^ srow;              // inverse-swizzled source slot

  f32x4 acc[MREP][NREP];
  #pragma unroll
  for (int m = 0; m < MREP; m++)
    #pragma unroll
    for (int n = 0; n < NREP; n++) acc[m][n] = f32x4{0.f, 0.f, 0.f, 0.f};

  auto STAGE = [&](int t, int s) {
    #pragma unroll
    for (int i = 0; i < CPW; i++) {
      int ch = w + 8 * i;                     // wave-uniform chunk id
      if (ch < ACH) {
        int r = ch * 8 + srow;
        gload16(A + (size_t)(gm0 + r) * K + t * 64 + sslot * 8, &As[s][ch * 512]);
      } else {
        int cb = ch - ACH;
        int r = cb * 8 + srow;
        gload16(Bm + (size_t)(gn0 + r) * K + t * 64 + sslot * 8, &Bs[s][cb * 512]);
      }
    }
  };

  STAGE(0, 0);
  for (int t = 0; t < NT; t++) {
    int cur = t & 1;
    if (t + 1 < NT) {
      STAGE(t + 1, cur ^ 1);
      if constexpr (CPW == 7)      { WAITV(7); }
      else if constexpr (CPW == 6) { WAITV(6); }
      else if constexpr (CPW == 5) { WAITV(5); }
      else                         { WAITV(4); }
    } else {
      WAITV(0);
    }
    FENCE();
    __builtin_amdgcn_s_barrier();             // buf[cur] staged & visible
    FENCE();

    f16x8 afr[MREP][2];
    #pragma unroll
    for (int m = 0; m < MREP; m++) {
      int r = wm * (BM_ / WM) + m * 16 + l15;
      #pragma unroll
      for (int kk = 0; kk < 2; kk++)
        afr[m][kk] = *(const f16x8*)(&As[cur][r * 64 + (((kk * 4 + g) ^ (r & 7)) * 8)]);
    }
    __builtin_amdgcn_s_setprio(1);
    #pragma unroll
    for (int n = 0; n < NREP; n++) {
      int r = wn * (BN_ / WN) + n * 16 + l15;
      f16x8 b0 = *(const f16x8*)(&Bs[cur][r * 64 + ((g ^ (r & 7)) * 8)]);
      f16x8 b1 = *(const f16x8*)(&Bs[cur][r * 64 + (((4 + g) ^ (r & 7)) * 8)]);
      #pragma unroll
      for (int m = 0; m < MREP; m++) {
        acc[m][n] = MFMA16(afr[m][0], b0, acc[m][n]);
        acc[m][n] = MFMA16(afr[m][1], b1, acc[m][n]);
      }
    }
    __builtin_amdgcn_s_setprio(0);
    LGKM0();
    __builtin_amdgcn_s_barrier();             // all reads of buf[cur] done
    FENCE();
  }

  #pragma unroll
  for (int m = 0; m < MREP; m++)
    #pragma unroll
    for (int j = 0; j < 4; j++) {
      int grow = gm0 + wm * (BM_ / WM) + m * 16 + g * 4 + j;
      float sc = rowscale[grow];
      #pragma unroll
      for (int n = 0; n < NREP; n++) {
        int gcol = gn0 + wn * (BN_ / WN) + n * 16 + l15;
        C[(size_t)grow * N + gcol] = (OT)(acc[m][n][j] * sc);
      }
    }
}

// ---------- 4. post: RMSNorm / RoPE for Q,K (V handled by vtrans) ----------
__global__ __launch_bounds__(512) void post_kernel(const f16_t* __restrict__ qkv,
                                                   const float* __restrict__ cosb,
                                                   const float* __restrict__ sinb,
                                                   const float* __restrict__ qnw,
                                                   const float* __restrict__ knw,
                                                   f16_t* __restrict__ Q,
                                                   f16_t* __restrict__ K)
{
  int m = blockIdx.x;
  int b = m >> 10, s = m & 1023;
  int tid = threadIdx.x;
  int w = tid >> 6, l = tid & 63;

  float c0 = cosb[(size_t)m * HD + l];
  float c1 = cosb[(size_t)m * HD + 64 + l];
  float s0 = sinb[(size_t)m * HD + l];
  float s1 = sinb[(size_t)m * HD + 64 + l];
  float qw0 = qnw[l], qw1 = qnw[64 + l];
  float kw0 = knw[l], kw1 = knw[64 + l];
  const f16_t* row = qkv + (size_t)m * NQKV;

  #pragma unroll
  for (int it = 0; it < 5; it++) {
    int slot = it * 8 + w;
    const f16_t* hp = row + slot * HD;
    float x0 = (float)hp[l];
    float x1 = (float)hp[l + 64];
    if (slot < NH) {                       // q: norm -> rope -> *1/sqrt(HD)
      int h = slot;
      float ss = wred_sum(x0 * x0 + x1 * x1);
      float r = 1.0f / sqrtf(ss * (1.0f / 128.0f) + 1e-6f);
      float xn0 = x0 * r * qw0, xn1 = x1 * r * qw1;
      float o0 = (xn0 * c0 - xn1 * s0) * 0.08838834764831845f;
      float o1 = (xn1 * c1 + xn0 * s1) * 0.08838834764831845f;
      f16_t* qp = Q + (((size_t)(b * NH + h)) * S_LEN + s) * HD;
      qp[l] = (f16_t)o0;
      qp[l + 64] = (f16_t)o1;
    } else {                               // k: norm -> quant -> rope
      int h = slot - NH;
      float ss = wred_sum(x0 * x0 + x1 * x1);
      float r = 1.0f / sqrtf(ss * (1.0f / 128.0f) + 1e-6f);
      float xn0 = x0 * r * kw0, xn1 = x1 * r * kw1;
      float mn = wred_min(fminf(xn0, xn1));
      float mx = wred_max(fmaxf(xn0, xn1));
      float scale = fmaxf(mx - mn, 1e-5f) / 15.0f;
      float base = fminf(fmaxf(rintf(-mn / scale), 0.f), 15.f);
      float q0 = (fminf(fmaxf(rintf(xn0 / scale) + base, 0.f), 15.f) - base) * scale;
      float q1 = (fminf(fmaxf(rintf(xn1 / scale) + base, 0.f), 15.f) - base) * scale;
      float o0 = q0 * c0 - q1 * s0;
      float o1 = q1 * c1 + q0 * s1;
      f16_t* kp = K + (((size_t)(b * NKV + h)) * S_LEN + s) * HD;
      kp[l] = (f16_t)o0;
      kp[l + 64] = (f16_t)o1;
    }
  }
}

// ---------- 4b. V: quantize + transpose via LDS (coalesced Vt writes) ----------
__global__ __launch_bounds__(256) void vtrans_kernel(const f16_t* __restrict__ qkv,
                                                     f16_t* __restrict__ Vt)
{
  __shared__ f16_t vs[128][129];   // +1 pad: column reads spread banks
  int blk = blockIdx.x;
  int st = blk & 7;                // s-tile
  int bh = blk >> 3;               // b*NKV + h
  int b = bh >> 3, h = bh & 7;
  int s0 = st * 128;
  int t = threadIdx.x;

  int r = t >> 1, hf = t & 1;
  const f16_t* src = qkv + ((size_t)(b * S_LEN + s0 + r)) * NQKV + (NH + NKV + h) * HD + hf * 64;
  #pragma unroll
  for (int i = 0; i < 8; i++)
    *(f16x8*)(&vs[r][hf * 64 + i * 8]) = *(const f16x8*)(src + i * 8);
  __syncthreads();

  float mn = 1e30f, mx = -1e30f;
  #pragma unroll
  for (int i = 0; i < 64; i++) {
    float x = (float)vs[r][hf * 64 + i];
    mn = fminf(mn, x); mx = fmaxf(mx, x);
  }
  mn = fminf(mn, __shfl_xor(mn, 1));
  mx = fmaxf(mx, __shfl_xor(mx, 1));
  float scale = fmaxf(mx - mn, 1e-5f) / 15.0f;
  float base = fminf(fmaxf(rintf(-mn / scale), 0.f), 15.f);
  #pragma unroll
  for (int i = 0; i < 64; i++) {
    int d = hf * 64 + i;
    float x = (float)vs[r][d];
    vs[r][d] = (f16_t)((fminf(fmaxf(rintf(x / scale) + base, 0.f), 15.f) - base) * scale);
  }
  __syncthreads();

  int wv = t >> 6, ln = t & 63;
  #pragma unroll
  for (int dd = 0; dd < 32; dd++) {
    int d = wv * 32 + dd;
    f16_t* orow = Vt + ((size_t)bh * HD + d) * S_LEN + s0;
    orow[ln] = vs[ln][d];
    orow[64 + ln] = vs[64 + ln][d];
  }
}

// ---------- 5. flash attention, f16 MFMA, 8 waves / 128 q-rows, dbuf K/V ----------
// grid 512, LDS 80KB -> 2 blocks/CU. Complementary qb mapping balances CU load.
// Writes f16 attn output (halves ao traffic; quant decisions unaffected).
__global__ __launch_bounds__(512) void attn_mfma(const f16_t* __restrict__ Q,
                                                 const f16_t* __restrict__ Kg,
                                                 const f16_t* __restrict__ Vg,
                                                 f16_t* __restrict__ O)
{
  __shared__ f16_t Ks[2][64 * 128];
  __shared__ f16_t Vs[2][128 * 64];
  __shared__ f16_t Ps[8 * 16 * 64];
  int tid = threadIdx.x;
  int w = tid >> 6, lane = tid & 63;
  int g = lane >> 4, l15 = lane & 15;
  int i = blockIdx.x;
  int base = i & 255, half = i >> 8;
  int bh = base & 63;
  int b = bh >> 5, h = bh & 31;
  int qbase = base >> 6;                 // 0..3
  int qb = half ? 7 - qbase : qbase;     // complementary pairing
  int kvh = h >> 2;
  int q0 = qb * 128;

  const f16_t* Qp = Q + (size_t)(b * NH + h) * S_LEN * HD;
  const f16_t* Kp = Kg + (size_t)(b * NKV + kvh) * S_LEN * HD;
  const f16_t* Vp = Vg + (size_t)(b * NKV + kvh) * HD * S_LEN;

  int qrow = q0 + w * 16 + l15;
  int myqmax = q0 + w * 16 + 15;
  f16x8 qf[4];
  #pragma unroll
  for (int c = 0; c < 4; c++)
    qf[c] = *(const f16x8*)(Qp + (size_t)qrow * HD + c * 32 + g * 8);

  f32x4 zf = {0.f, 0.f, 0.f, 0.f};
  f32x4 oacc[8];
  #pragma unroll
  for (int nd = 0; nd < 8; nd++) oacc[nd] = zf;
  float mrun[4], lrun[4];
  #pragma unroll
  for (int j = 0; j < 4; j++) { mrun[j] = -INFINITY; lrun[j] = 0.f; }

  int vrow = lane >> 3, vslot = lane & 7;
  auto STAGEKV = [&](int it, int bb) {
    int kt = it * 64;
    #pragma unroll
    for (int ii = 0; ii < 2; ii++) {
      int c = w + 8 * ii;
      int row = c * 4 + g;
      gload16(Kp + (size_t)(kt + row) * HD + (l15 ^ (row & 7)) * 8, &Ks[bb][c * 512]);
    }
    #pragma unroll
    for (int ii = 0; ii < 2; ii++) {
      int c = w + 8 * ii;
      int row = c * 8 + vrow;
      gload16(Vp + (size_t)row * S_LEN + kt + (vslot ^ (row & 7)) * 8, &Vs[bb][c * 512]);
    }
  };

  f16_t* pw = Ps + w * 1024;
  int ntiles = 2 * qb + 2;
  STAGEKV(0, 0);
  for (int it = 0; it < ntiles; it++) {
    int cur = it & 1;
    if (it + 1 < ntiles) {
      STAGEKV(it + 1, cur ^ 1);
      WAITV(4);
    } else {
      WAITV(0);
    }
    FENCE();
    __builtin_amdgcn_s_barrier();
    FENCE();

    int kt = it * 64;
    if (kt <= myqmax) {
      // QK^T: S[16q][64k]
      f32x4 sv[4];
      #pragma unroll
      for (int nk = 0; nk < 4; nk++) sv[nk] = zf;
      __builtin_amdgcn_s_setprio(1);
      #pragma unroll
      for (int nk = 0; nk < 4; nk++) {
        int krow = nk * 16 + l15;
        #pragma unroll
        for (int c = 0; c < 4; c++) {
          f16x8 kf = *(const f16x8*)(&Ks[cur][krow * 128 + (((c * 4 + g) ^ (krow & 7)) * 8)]);
          sv[nk] = MFMA16(qf[c], kf, sv[nk]);
        }
      }
      __builtin_amdgcn_s_setprio(0);
      // causal mask
      #pragma unroll
      for (int nk = 0; nk < 4; nk++) {
        int kcol = kt + nk * 16 + l15;
        #pragma unroll
        for (int j = 0; j < 4; j++) {
          int qr = q0 + w * 16 + g * 4 + j;
          if (kcol > qr) sv[nk][j] = -1e30f;
        }
      }
      // online softmax
      float alpha[4];
      #pragma unroll
      for (int j = 0; j < 4; j++) {
        float mr = fmaxf(fmaxf(sv[0][j], sv[1][j]), fmaxf(sv[2][j], sv[3][j]));
        mr = fmaxf(mr, __shfl_xor(mr, 1));
        mr = fmaxf(mr, __shfl_xor(mr, 2));
        mr = fmaxf(mr, __shfl_xor(mr, 4));
        mr = fmaxf(mr, __shfl_xor(mr, 8));
        float mnew = fmaxf(mrun[j], mr);
        alpha[j] = __expf(mrun[j] - mnew);
        float lt = 0.f;
        #pragma unroll
        for (int nk = 0; nk < 4; nk++) {
          float p = __expf(sv[nk][j] - mnew);
          sv[nk][j] = p;
          lt += p;
        }
        lt += __shfl_xor(lt, 1);
        lt += __shfl_xor(lt, 2);
        lt += __shfl_xor(lt, 4);
        lt += __shfl_xor(lt, 8);
        lrun[j] = lrun[j] * alpha[j] + lt;
        mrun[j] = mnew;
      }
      // write P (f16, swizzled rows of 64 elems)
      #pragma unroll
      for (int j = 0; j < 4; j++) {
        int ql = g * 4 + j;
        #pragma unroll
        for (int nk = 0; nk < 4; nk++) {
          int kl = nk * 16 + l15;
          int ss = (kl >> 3) ^ (ql & 7);
          pw[ql * 64 + ss * 8 + (kl & 7)] = (f16_t)sv[nk][j];
        }
      }
      // rescale O
      #pragma unroll
      for (int nd = 0; nd < 8; nd++)
        #pragma unroll
        for (int j = 0; j < 4; j++) oacc[nd][j] *= alpha[j];
      // PV: O[16q][128d] += P[16q][64k] * V[64k][128d]
      __builtin_amdgcn_s_setprio(1);
      #pragma unroll
      for (int kc = 0; kc < 2; kc++) {
        f16x8 pf = *(const f16x8*)(pw + l15 * 64 + ((kc * 4 + g) ^ (l15 & 7)) * 8);
        #pragma unroll
        for (int nd = 0; nd < 8; nd++) {
          int d = nd * 16 + l15;
          f16x8 vf = *(const f16x8*)(&Vs[cur][d * 64 + (((kc * 4 + g) ^ (d & 7)) * 8)]);
          oacc[nd] = MFMA16(pf, vf, oacc[nd]);
        }
      }
      __builtin_amdgcn_s_setprio(0);
      LGKM0();
    }
    __builtin_amdgcn_s_barrier();
    FENCE();
  }
  // epilogue: write (B,S,NH*HD) f16
  #pragma unroll
  for (int j = 0; j < 4; j++) {
    float invl = 1.0f / lrun[j];
    f16_t* orow = O + ((size_t)(b * S_LEN) + q0 + w * 16 + g * 4 + j) * (NH * HD) + h * HD + l15;
    #pragma unroll
    for (int nd = 0; nd < 8; nd++) orow[nd * 16] = (f16_t)(oacc[nd][j] * invl);
  }
}

// ---------- launcher ----------
extern "C" void kernel_launch(void* const* d_in, const int* in_sizes, int n_in,
                              void* d_out, int out_size, void* d_ws, size_t ws_size,
                              hipStream_t stream) {
  const float* hidden = (const float*)d_in[0];
  const float* cosb   = (const float*)d_in[1];
  const float* sinb   = (const float*)d_in[2];
  const float* Wq     = (const float*)d_in[3];
  const float* Wk     = (const float*)d_in[4];
  const float* Wv     = (const float*)d_in[5];
  const float* Wo     = (const float*)d_in[6];
  const float* qnw    = (const float*)d_in[7];
  const float* knw    = (const float*)d_in[8];
  const int*   r_qkv  = (const int*)d_in[9];
  const int*   r_o    = (const int*)d_in[10];
  float* out = (float*)d_out;

  f16_t* xq   = (f16_t*)d_ws;                                    // [2048][4096] f16
  f16_t* wcat = xq + (size_t)M_ROWS * HID;                       // [6144][4096] f16
  f16_t* woq  = wcat + (size_t)NQKV * HID;                       // [4096][4096] f16
  f16_t* qkv  = woq + (size_t)HID * HID;                         // [2048][6144] f16
  f16_t* Qb   = qkv + (size_t)M_ROWS * NQKV;                     // [2*32*1024][128] f16
  f16_t* Kb   = Qb + (size_t)2 * NH * S_LEN * HD;                // [2*8*1024][128] f16
  f16_t* Vt   = Kb + (size_t)2 * NKV * S_LEN * HD;               // [2*8][128][1024] f16
  f16_t* ao   = Vt + (size_t)2 * NKV * S_LEN * HD;               // [2048][4096] f16
  float* sa1  = (float*)(ao + (size_t)M_ROWS * HID);             // [2048] f32
  float* sa2  = sa1 + M_ROWS;                                    // [2048] f32
  size_t needed = (size_t)((char*)(sa2 + M_ROWS) - (char*)d_ws);
  if (ws_size < needed) return;
  f16_t* oq = xq;      // alias: quantized attn output (xq dead after QKV GEMM)

  aquant_kernel<float><<<M_ROWS, 256, 0, stream>>>(hidden, r_qkv, xq, sa1);
  wquant_all<<<NQKV + HID, 256, 0, stream>>>(Wq, Wk, Wv, Wo, r_qkv, r_o, wcat, woq);
  // QKV: 128x192 tiles (LDS 80KB -> 2 blocks/CU), waves 2Mx4N, grid 32x16 = 512
  gemm_bt<128, 192, 2, f16_t><<<dim3(NQKV / 192, M_ROWS / 128), 512, 0, stream>>>(xq, wcat, qkv, sa1, NQKV, HID);
  post_kernel<<<M_ROWS, 512, 0, stream>>>(qkv, cosb, sinb, qnw, knw, Qb, Kb);
  vtrans_kernel<<<2 * NKV * 8, 256, 0, stream>>>(qkv, Vt);
  attn_mfma<<<512, 512, 0, stream>>>(Qb, Kb, Vt, ao);
  aquant_kernel<f16_t><<<M_ROWS, 256, 0, stream>>>(ao, r_o, oq, sa2);
  // O-proj: 128x128 tiles (LDS 64KB -> 2 blocks/CU), waves 2Mx4N, grid 32x16 = 512
  gemm_bt<128, 128, 2, float><<<dim3(HID / 128, M_ROWS / 128), 512, 0, stream>>>(oq, woq, out, sa2, HID, HID);
}

// Round 18
// 291.679 us; speedup vs baseline: 1.4582x; 1.0184x over previous
//
#include <hip/hip_runtime.h>
#include <hip/hip_bf16.h>
#include <cstdint>

#define S_LEN 1024
#define HID   4096
#define NH    32
#define NKV   8
#define HD    128
#define NLOW  3968      // HID - SEL (= 248*16)
#define M_ROWS 2048     // B*S
#define NQKV  6144      // (NH+2*NKV)*HD

typedef _Float16 f16_t;
typedef _Float16 f16x8 __attribute__((ext_vector_type(8)));
typedef float    f32x4 __attribute__((ext_vector_type(4)));

#define MFMA16(a,b,c) __builtin_amdgcn_mfma_f32_16x16x32_f16(a,b,c,0,0,0)

__device__ inline void gload16(const void* g, void* l) {
  __builtin_amdgcn_global_load_lds(
      (const __attribute__((address_space(1))) void*)g,
      (__attribute__((address_space(3))) void*)l, 16, 0, 0);
}

#define WAITV(n) asm volatile("s_waitcnt vmcnt(" #n ")" ::: "memory")
#define LGKM0()  asm volatile("s_waitcnt lgkmcnt(0)" ::: "memory")
#define FENCE()  asm volatile("" ::: "memory")

// ---------- wave reductions (64-wide) ----------
__device__ inline float wred_max(float v){ for(int o=32;o;o>>=1) v=fmaxf(v,__shfl_xor(v,o)); return v; }
__device__ inline float wred_min(float v){ for(int o=32;o;o>>=1) v=fminf(v,__shfl_xor(v,o)); return v; }
__device__ inline float wred_sum(float v){ for(int o=32;o;o>>=1) v+=__shfl_xor(v,o); return v; }

// ---------- activation quant body (f32 input from LDS stage) ----------
__device__ inline void aquant_body_f32(const float* __restrict__ xrowbase,
                                       const int* __restrict__ reorder,
                                       f16_t* __restrict__ orow,
                                       float* __restrict__ sarr, int row,
                                       int t, float* xs, float* red)
{
  const f32x4* xr4 = (const f32x4*)xrowbase;
  f32x4* xs4 = (f32x4*)xs;
  #pragma unroll
  for (int i = 0; i < 4; i++)
    xs4[t + i * 256] = xr4[t + i * 256];
  __syncthreads();

  int c0 = t * 16;
  float v[16];
  #pragma unroll
  for (int j = 0; j < 16; j++)
    v[j] = xs[reorder[c0 + j]];

  float amax = 0.f;
  if (c0 < NLOW) {
    #pragma unroll
    for (int j = 0; j < 16; j++) amax = fmaxf(amax, fabsf(v[j]));
  }
  amax = wred_max(amax);
  if ((t & 63) == 0) red[t >> 6] = amax;
  __syncthreads();
  float scale = fmaxf(fmaxf(fmaxf(red[0], red[1]), fmaxf(red[2], red[3])), 1e-5f) / 127.0f;
  if (t == 0) sarr[row] = scale;

  f16x8 o0, o1;
  if (c0 < NLOW) {
    #pragma unroll
    for (int j = 0; j < 8; j++) {
      o0[j] = (f16_t)fminf(fmaxf(rintf(v[j] / scale), -128.f), 127.f);
      o1[j] = (f16_t)fminf(fmaxf(rintf(v[j + 8] / scale), -128.f), 127.f);
    }
  } else {
    #pragma unroll
    for (int j = 0; j < 8; j++) { o0[j] = (f16_t)(v[j] / scale); o1[j] = (f16_t)(v[j + 8] / scale); }
  }
  *(f16x8*)(orow + c0) = o0;
  *(f16x8*)(orow + c0 + 8) = o1;
}

// ---------- aquant for f16 input (attn output) ----------
__global__ __launch_bounds__(256) void aquant16_kernel(const f16_t* __restrict__ X,
                                                       const int* __restrict__ reorder,
                                                       f16_t* __restrict__ out,
                                                       float* __restrict__ sarr)
{
  __shared__ float xs[HID];
  __shared__ float red[4];
  int row = blockIdx.x;
  int t = threadIdx.x;
  const f16x8* xr8 = (const f16x8*)(X + (size_t)row * HID);
  #pragma unroll
  for (int i = 0; i < 2; i++) {
    f16x8 v8 = xr8[t + i * 256];
    #pragma unroll
    for (int j = 0; j < 8; j++)
      xs[(t + i * 256) * 8 + j] = (float)v8[j];
  }
  __syncthreads();

  int c0 = t * 16;
  float v[16];
  #pragma unroll
  for (int j = 0; j < 16; j++)
    v[j] = xs[reorder[c0 + j]];

  float amax = 0.f;
  if (c0 < NLOW) {
    #pragma unroll
    for (int j = 0; j < 16; j++) amax = fmaxf(amax, fabsf(v[j]));
  }
  amax = wred_max(amax);
  if ((t & 63) == 0) red[t >> 6] = amax;
  __syncthreads();
  float scale = fmaxf(fmaxf(fmaxf(red[0], red[1]), fmaxf(red[2], red[3])), 1e-5f) / 127.0f;
  if (t == 0) sarr[row] = scale;

  f16_t* orow = out + (size_t)row * HID;
  f16x8 o0, o1;
  if (c0 < NLOW) {
    #pragma unroll
    for (int j = 0; j < 8; j++) {
      o0[j] = (f16_t)fminf(fmaxf(rintf(v[j] / scale), -128.f), 127.f);
      o1[j] = (f16_t)fminf(fmaxf(rintf(v[j + 8] / scale), -128.f), 127.f);
    }
  } else {
    #pragma unroll
    for (int j = 0; j < 8; j++) { o0[j] = (f16_t)(v[j] / scale); o1[j] = (f16_t)(v[j + 8] / scale); }
  }
  *(f16x8*)(orow + c0) = o0;
  *(f16x8*)(orow + c0 + 8) = o1;
}

// ---------- weight quant body ----------
__device__ inline void wquant_body(const float* __restrict__ wrowbase,
                                   const int* __restrict__ reorder,
                                   f16_t* __restrict__ orow, int t, float* xs)
{
  const f32x4* wrow4 = (const f32x4*)wrowbase;
  f32x4* xs4 = (f32x4*)xs;
  #pragma unroll
  for (int i = 0; i < 4; i++)
    xs4[t + i * 256] = wrow4[t + i * 256];
  __syncthreads();

  int c0 = t * 16;
  float v[16];
  #pragma unroll
  for (int j = 0; j < 16; j++)
    v[j] = xs[reorder[c0 + j]];

  f16x8 o0, o1;
  if (c0 < NLOW) {
    float mn = v[0], mx = v[0];
    #pragma unroll
    for (int j = 1; j < 16; j++) { mn = fminf(mn, v[j]); mx = fmaxf(mx, v[j]); }
    #pragma unroll
    for (int o = 1; o <= 4; o <<= 1) {
      mn = fminf(mn, __shfl_xor(mn, o));
      mx = fmaxf(mx, __shfl_xor(mx, o));
    }
    float scale = fmaxf(mx - mn, 1e-5f) / 15.0f;
    float base = fminf(fmaxf(rintf(-mn / scale), 0.f), 15.f);
    #pragma unroll
    for (int j = 0; j < 8; j++) {
      o0[j] = (f16_t)((fminf(fmaxf(rintf(v[j] / scale) + base, 0.f), 15.f) - base) * scale);
      o1[j] = (f16_t)((fminf(fmaxf(rintf(v[j + 8] / scale) + base, 0.f), 15.f) - base) * scale);
    }
  } else {
    #pragma unroll
    for (int j = 0; j < 8; j++) { o0[j] = (f16_t)v[j]; o1[j] = (f16_t)v[j + 8]; }
  }
  *(f16x8*)(orow + c0) = o0;
  *(f16x8*)(orow + c0 + 8) = o1;
}

// ---------- all preprocessing in ONE launch: 4 weight matrices + hidden aquant ----------
// rows 0..4095 Wq, 4096..5119 Wk, 5120..6143 Wv, 6144..10239 Wo, 10240..12287 aquant(hidden)
__global__ __launch_bounds__(256) void prep_all(const float* __restrict__ Wq,
                                                const float* __restrict__ Wk,
                                                const float* __restrict__ Wv,
                                                const float* __restrict__ Wo,
                                                const float* __restrict__ hidden,
                                                const int* __restrict__ r_qkv,
                                                const int* __restrict__ r_o,
                                                f16_t* __restrict__ wcat,
                                                f16_t* __restrict__ woq,
                                                f16_t* __restrict__ xq,
                                                float* __restrict__ sa1)
{
  __shared__ float xs[HID];
  __shared__ float red[4];
  int row = blockIdx.x;
  int t = threadIdx.x;
  if (row < 10240) {
    const float* src; const int* reo; f16_t* dst;
    if (row < 4096)      { src = Wq + (size_t)row * HID;          reo = r_qkv; dst = wcat + (size_t)row * HID; }
    else if (row < 5120) { src = Wk + (size_t)(row - 4096) * HID; reo = r_qkv; dst = wcat + (size_t)row * HID; }
    else if (row < 6144) { src = Wv + (size_t)(row - 5120) * HID; reo = r_qkv; dst = wcat + (size_t)row * HID; }
    else                 { src = Wo + (size_t)(row - 6144) * HID; reo = r_o;   dst = woq + (size_t)(row - 6144) * HID; }
    wquant_body(src, reo, dst, t, xs);
  } else {
    int r = row - 10240;
    aquant_body_f32(hidden + (size_t)r * HID, r_qkv, xq + (size_t)r * HID, sa1, r, t, xs, red);
  }
}

// ---------- f16 MFMA GEMM 16x16x32 (BK=64 dbuf, counted vmcnt, 2 blocks/CU) ----------
template<int BM_, int BN_, int WM, typename OT>
__global__ __launch_bounds__(512, 4) void gemm_bt(const f16_t* __restrict__ A,
                                                  const f16_t* __restrict__ Bm,
                                                  OT* __restrict__ C,
                                                  const float* __restrict__ rowscale,
                                                  int N, int K)
{
  constexpr int WN   = 8 / WM;
  constexpr int MREP = BM_ / WM / 16;   // per-wave M fragments
  constexpr int NREP = BN_ / WN / 16;   // per-wave N fragments
  constexpr int ACH  = BM_ / 8;         // A chunks (1KB = 8 rows x 64 f16) per K-tile
  constexpr int TCH  = ACH + BN_ / 8;
  constexpr int CPW  = TCH / 8;         // chunks per wave
  static_assert(TCH % 8 == 0, "chunks must split evenly across 8 waves");
  __shared__ f16_t As[2][BM_ * 64];
  __shared__ f16_t Bs[2][BN_ * 64];

  int tid = threadIdx.x;
  int w = tid >> 6, lane = tid & 63;
  int g = lane >> 4, l15 = lane & 15;
  int wm = w / WN, wn = w % WN;
  int gm0 = blockIdx.y * BM_, gn0 = blockIdx.x * BN_;
  int NT = K >> 6;
  int srow = lane >> 3;                       // 0..7 row within chunk
  int sslot = (lane & 7) ^ srow;              // inverse-swizzled source slot

  f32x4 acc[MREP][NREP];
  #pragma unroll
  for (int m = 0; m < MREP; m++)
    #pragma unroll
    for (int n = 0; n < NREP; n++) acc[m][n] = f32x4{0.f, 0.f, 0.f, 0.f};

  auto STAGE = [&](int t, int s) {
    #pragma unroll
    for (int i = 0; i < CPW; i++) {
      int ch = w + 8 * i;                     // wave-uniform chunk id
      if (ch < ACH) {
        int r = ch * 8 + srow;
        gload16(A + (size_t)(gm0 + r) * K + t * 64 + sslot * 8, &As[s][ch * 512]);
      } else {
        int cb = ch - ACH;
        int r = cb * 8 + srow;
        gload16(Bm + (size_t)(gn0 + r) * K + t * 64 + sslot * 8, &Bs[s][cb * 512]);
      }
    }
  };

  STAGE(0, 0);
  for (int t = 0; t < NT; t++) {
    int cur = t & 1;
    if (t + 1 < NT) {
      STAGE(t + 1, cur ^ 1);
      if constexpr (CPW == 7)      { WAITV(7); }
      else if constexpr (CPW == 6) { WAITV(6); }
      else if constexpr (CPW == 5) { WAITV(5); }
      else                         { WAITV(4); }
    } else {
      WAITV(0);
    }
    FENCE();
    __builtin_amdgcn_s_barrier();             // buf[cur] staged & visible
    FENCE();

    f16x8 afr[MREP][2];
    #pragma unroll
    for (int m = 0; m < MREP; m++) {
      int r = wm * (BM_ / WM) + m * 16 + l15;
      #pragma unroll
      for (int kk = 0; kk < 2; kk++)
        afr[m][kk] = *(const f16x8*)(&As[cur][r * 64 + (((kk * 4 + g) ^ (r & 7)) * 8)]);
    }
    __builtin_amdgcn_s_setprio(1);
    #pragma unroll
    for (int n = 0; n < NREP; n++) {
      int r = wn * (BN_ / WN) + n * 16 + l15;
      f16x8 b0 = *(const f16x8*)(&Bs[cur][r * 64 + ((g ^ (r & 7)) * 8)]);
      f16x8 b1 = *(const f16x8*)(&Bs[cur][r * 64 + (((4 + g) ^ (r & 7)) * 8)]);
      #pragma unroll
      for (int m = 0; m < MREP; m++) {
        acc[m][n] = MFMA16(afr[m][0], b0, acc[m][n]);
        acc[m][n] = MFMA16(afr[m][1], b1, acc[m][n]);
      }
    }
    __builtin_amdgcn_s_setprio(0);
    LGKM0();
    __builtin_amdgcn_s_barrier();             // all reads of buf[cur] done
    FENCE();
  }

  #pragma unroll
  for (int m = 0; m < MREP; m++)
    #pragma unroll
    for (int j = 0; j < 4; j++) {
      int grow = gm0 + wm * (BM_ / WM) + m * 16 + g * 4 + j;
      float sc = rowscale[grow];
      #pragma unroll
      for (int n = 0; n < NREP; n++) {
        int gcol = gn0 + wn * (BN_ / WN) + n * 16 + l15;
        C[(size_t)grow * N + gcol] = (OT)(acc[m][n][j] * sc);
      }
    }
}

// ---------- post: RMSNorm / RoPE for Q,K (V handled by vtrans) ----------
__global__ __launch_bounds__(512) void post_kernel(const f16_t* __restrict__ qkv,
                                                   const float* __restrict__ cosb,
                                                   const float* __restrict__ sinb,
                                                   const float* __restrict__ qnw,
                                                   const float* __restrict__ knw,
                                                   f16_t* __restrict__ Q,
                                                   f16_t* __restrict__ K)
{
  int m = blockIdx.x;
  int b = m >> 10, s = m & 1023;
  int tid = threadIdx.x;
  int w = tid >> 6, l = tid & 63;

  float c0 = cosb[(size_t)m * HD + l];
  float c1 = cosb[(size_t)m * HD + 64 + l];
  float s0 = sinb[(size_t)m * HD + l];
  float s1 = sinb[(size_t)m * HD + 64 + l];
  float qw0 = qnw[l], qw1 = qnw[64 + l];
  float kw0 = knw[l], kw1 = knw[64 + l];
  const f16_t* row = qkv + (size_t)m * NQKV;

  #pragma unroll
  for (int it = 0; it < 5; it++) {
    int slot = it * 8 + w;
    const f16_t* hp = row + slot * HD;
    float x0 = (float)hp[l];
    float x1 = (float)hp[l + 64];
    if (slot < NH) {                       // q: norm -> rope -> *1/sqrt(HD)
      int h = slot;
      float ss = wred_sum(x0 * x0 + x1 * x1);
      float r = 1.0f / sqrtf(ss * (1.0f / 128.0f) + 1e-6f);
      float xn0 = x0 * r * qw0, xn1 = x1 * r * qw1;
      float o0 = (xn0 * c0 - xn1 * s0) * 0.08838834764831845f;
      float o1 = (xn1 * c1 + xn0 * s1) * 0.08838834764831845f;
      f16_t* qp = Q + (((size_t)(b * NH + h)) * S_LEN + s) * HD;
      qp[l] = (f16_t)o0;
      qp[l + 64] = (f16_t)o1;
    } else {                               // k: norm -> quant -> rope
      int h = slot - NH;
      float ss = wred_sum(x0 * x0 + x1 * x1);
      float r = 1.0f / sqrtf(ss * (1.0f / 128.0f) + 1e-6f);
      float xn0 = x0 * r * kw0, xn1 = x1 * r * kw1;
      float mn = wred_min(fminf(xn0, xn1));
      float mx = wred_max(fmaxf(xn0, xn1));
      float scale = fmaxf(mx - mn, 1e-5f) / 15.0f;
      float base = fminf(fmaxf(rintf(-mn / scale), 0.f), 15.f);
      float q0 = (fminf(fmaxf(rintf(xn0 / scale) + base, 0.f), 15.f) - base) * scale;
      float q1 = (fminf(fmaxf(rintf(xn1 / scale) + base, 0.f), 15.f) - base) * scale;
      float o0 = q0 * c0 - q1 * s0;
      float o1 = q1 * c1 + q0 * s1;
      f16_t* kp = K + (((size_t)(b * NKV + h)) * S_LEN + s) * HD;
      kp[l] = (f16_t)o0;
      kp[l + 64] = (f16_t)o1;
    }
  }
}

// ---------- V: quantize + transpose via LDS (coalesced Vt writes) ----------
__global__ __launch_bounds__(256) void vtrans_kernel(const f16_t* __restrict__ qkv,
                                                     f16_t* __restrict__ Vt)
{
  __shared__ f16_t vs[128][129];   // +1 pad: column reads spread banks
  int blk = blockIdx.x;
  int st = blk & 7;                // s-tile
  int bh = blk >> 3;               // b*NKV + h
  int b = bh >> 3, h = bh & 7;
  int s0 = st * 128;
  int t = threadIdx.x;

  int r = t >> 1, hf = t & 1;
  const f16_t* src = qkv + ((size_t)(b * S_LEN + s0 + r)) * NQKV + (NH + NKV + h) * HD + hf * 64;
  #pragma unroll
  for (int i = 0; i < 8; i++)
    *(f16x8*)(&vs[r][hf * 64 + i * 8]) = *(const f16x8*)(src + i * 8);
  __syncthreads();

  float mn = 1e30f, mx = -1e30f;
  #pragma unroll
  for (int i = 0; i < 64; i++) {
    float x = (float)vs[r][hf * 64 + i];
    mn = fminf(mn, x); mx = fmaxf(mx, x);
  }
  mn = fminf(mn, __shfl_xor(mn, 1));
  mx = fmaxf(mx, __shfl_xor(mx, 1));
  float scale = fmaxf(mx - mn, 1e-5f) / 15.0f;
  float base = fminf(fmaxf(rintf(-mn / scale), 0.f), 15.f);
  #pragma unroll
  for (int i = 0; i < 64; i++) {
    int d = hf * 64 + i;
    float x = (float)vs[r][d];
    vs[r][d] = (f16_t)((fminf(fmaxf(rintf(x / scale) + base, 0.f), 15.f) - base) * scale);
  }
  __syncthreads();

  int wv = t >> 6, ln = t & 63;
  #pragma unroll
  for (int dd = 0; dd < 32; dd++) {
    int d = wv * 32 + dd;
    f16_t* orow = Vt + ((size_t)bh * HD + d) * S_LEN + s0;
    orow[ln] = vs[ln][d];
    orow[64 + ln] = vs[64 + ln][d];
  }
}

// ---------- flash attention, f16 MFMA, 8 waves / 128 q-rows, dbuf K/V ----------
// grid 512, LDS 80KB -> 2 blocks/CU. Complementary qb mapping balances CU load.
// Defer-max (T13, THR=8): skip O-rescale when per-tile max growth <= 8.
__global__ __launch_bounds__(512) void attn_mfma(const f16_t* __restrict__ Q,
                                                 const f16_t* __restrict__ Kg,
                                                 const f16_t* __restrict__ Vg,
                                                 f16_t* __restrict__ O)
{
  __shared__ f16_t Ks[2][64 * 128];
  __shared__ f16_t Vs[2][128 * 64];
  __shared__ f16_t Ps[8 * 16 * 64];
  int tid = threadIdx.x;
  int w = tid >> 6, lane = tid & 63;
  int g = lane >> 4, l15 = lane & 15;
  int i = blockIdx.x;
  int base = i & 255, half = i >> 8;
  int bh = base & 63;
  int b = bh >> 5, h = bh & 31;
  int qbase = base >> 6;                 // 0..3
  int qb = half ? 7 - qbase : qbase;     // complementary pairing
  int kvh = h >> 2;
  int q0 = qb * 128;

  const f16_t* Qp = Q + (size_t)(b * NH + h) * S_LEN * HD;
  const f16_t* Kp = Kg + (size_t)(b * NKV + kvh) * S_LEN * HD;
  const f16_t* Vp = Vg + (size_t)(b * NKV + kvh) * HD * S_LEN;

  int qrow = q0 + w * 16 + l15;
  int myqmax = q0 + w * 16 + 15;
  f16x8 qf[4];
  #pragma unroll
  for (int c = 0; c < 4; c++)
    qf[c] = *(const f16x8*)(Qp + (size_t)qrow * HD + c * 32 + g * 8);

  f32x4 zf = {0.f, 0.f, 0.f, 0.f};
  f32x4 oacc[8];
  #pragma unroll
  for (int nd = 0; nd < 8; nd++) oacc[nd] = zf;
  float mrun[4], lrun[4];
  #pragma unroll
  for (int j = 0; j < 4; j++) { mrun[j] = -INFINITY; lrun[j] = 0.f; }

  int vrow = lane >> 3, vslot = lane & 7;
  auto STAGEKV = [&](int it, int bb) {
    int kt = it * 64;
    #pragma unroll
    for (int ii = 0; ii < 2; ii++) {
      int c = w + 8 * ii;
      int row = c * 4 + g;
      gload16(Kp + (size_t)(kt + row) * HD + (l15 ^ (row & 7)) * 8, &Ks[bb][c * 512]);
    }
    #pragma unroll
    for (int ii = 0; ii < 2; ii++) {
      int c = w + 8 * ii;
      int row = c * 8 + vrow;
      gload16(Vp + (size_t)row * S_LEN + kt + (vslot ^ (row & 7)) * 8, &Vs[bb][c * 512]);
    }
  };

  f16_t* pw = Ps + w * 1024;
  int ntiles = 2 * qb + 2;
  STAGEKV(0, 0);
  for (int it = 0; it < ntiles; it++) {
    int cur = it & 1;
    if (it + 1 < ntiles) {
      STAGEKV(it + 1, cur ^ 1);
      WAITV(4);
    } else {
      WAITV(0);
    }
    FENCE();
    __builtin_amdgcn_s_barrier();
    FENCE();

    int kt = it * 64;
    if (kt <= myqmax) {
      // QK^T: S[16q][64k]
      f32x4 sv[4];
      #pragma unroll
      for (int nk = 0; nk < 4; nk++) sv[nk] = zf;
      __builtin_amdgcn_s_setprio(1);
      #pragma unroll
      for (int nk = 0; nk < 4; nk++) {
        int krow = nk * 16 + l15;
        #pragma unroll
        for (int c = 0; c < 4; c++) {
          f16x8 kf = *(const f16x8*)(&Ks[cur][krow * 128 + (((c * 4 + g) ^ (krow & 7)) * 8)]);
          sv[nk] = MFMA16(qf[c], kf, sv[nk]);
        }
      }
      __builtin_amdgcn_s_setprio(0);
      // causal mask
      #pragma unroll
      for (int nk = 0; nk < 4; nk++) {
        int kcol = kt + nk * 16 + l15;
        #pragma unroll
        for (int j = 0; j < 4; j++) {
          int qr = q0 + w * 16 + g * 4 + j;
          if (kcol > qr) sv[nk][j] = -1e30f;
        }
      }
      // row maxima of this tile
      float mr[4];
      bool need = false;
      #pragma unroll
      for (int j = 0; j < 4; j++) {
        float m2 = fmaxf(fmaxf(sv[0][j], sv[1][j]), fmaxf(sv[2][j], sv[3][j]));
        m2 = fmaxf(m2, __shfl_xor(m2, 1));
        m2 = fmaxf(m2, __shfl_xor(m2, 2));
        m2 = fmaxf(m2, __shfl_xor(m2, 4));
        m2 = fmaxf(m2, __shfl_xor(m2, 8));
        mr[j] = m2;
        need = need || (m2 > mrun[j] + 8.f);
      }
      // defer-max: rescale only when max grew beyond THR=8 anywhere in the wave
      if (__builtin_amdgcn_ballot_w64(need) != 0ull) {
        #pragma unroll
        for (int j = 0; j < 4; j++) {
          float mnew = fmaxf(mrun[j], mr[j]);
          float alpha = __expf(mrun[j] - mnew);   // first tile: exp(-inf)=0
          lrun[j] *= alpha;
          #pragma unroll
          for (int nd = 0; nd < 8; nd++) oacc[nd][j] *= alpha;
          mrun[j] = mnew;
        }
      }
      // P = exp(S - mrun)  (bounded by e^8 when deferred)
      #pragma unroll
      for (int j = 0; j < 4; j++) {
        float lt = 0.f;
        #pragma unroll
        for (int nk = 0; nk < 4; nk++) {
          float p = __expf(sv[nk][j] - mrun[j]);
          sv[nk][j] = p;
          lt += p;
        }
        lt += __shfl_xor(lt, 1);
        lt += __shfl_xor(lt, 2);
        lt += __shfl_xor(lt, 4);
        lt += __shfl_xor(lt, 8);
        lrun[j] += lt;
      }
      // write P (f16, swizzled rows of 64 elems)
      #pragma unroll
      for (int j = 0; j < 4; j++) {
        int ql = g * 4 + j;
        #pragma unroll
        for (int nk = 0; nk < 4; nk++) {
          int kl = nk * 16 + l15;
          int ss = (kl >> 3) ^ (ql & 7);
          pw[ql * 64 + ss * 8 + (kl & 7)] = (f16_t)sv[nk][j];
        }
      }
      // PV: O[16q][128d] += P[16q][64k] * V[64k][128d]
      __builtin_amdgcn_s_setprio(1);
      #pragma unroll
      for (int kc = 0; kc < 2; kc++) {
        f16x8 pf = *(const f16x8*)(pw + l15 * 64 + ((kc * 4 + g) ^ (l15 & 7)) * 8);
        #pragma unroll
        for (int nd = 0; nd < 8; nd++) {
          int d = nd * 16 + l15;
          f16x8 vf = *(const f16x8*)(&Vs[cur][d * 64 + (((kc * 4 + g) ^ (d & 7)) * 8)]);
          oacc[nd] = MFMA16(pf, vf, oacc[nd]);
        }
      }
      __builtin_amdgcn_s_setprio(0);
      LGKM0();
    }
    __builtin_amdgcn_s_barrier();
    FENCE();
  }
  // epilogue: write (B,S,NH*HD) f16
  #pragma unroll
  for (int j = 0; j < 4; j++) {
    float invl = 1.0f / lrun[j];
    f16_t* orow = O + ((size_t)(b * S_LEN) + q0 + w * 16 + g * 4 + j) * (NH * HD) + h * HD + l15;
    #pragma unroll
    for (int nd = 0; nd < 8; nd++) orow[nd * 16] = (f16_t)(oacc[nd][j] * invl);
  }
}

// ---------- launcher ----------
extern "C" void kernel_launch(void* const* d_in, const int* in_sizes, int n_in,
                              void* d_out, int out_size, void* d_ws, size_t ws_size,
                              hipStream_t stream) {
  const float* hidden = (const float*)d_in[0];
  const float* cosb   = (const float*)d_in[1];
  const float* sinb   = (const float*)d_in[2];
  const float* Wq     = (const float*)d_in[3];
  const float* Wk     = (const float*)d_in[4];
  const float* Wv     = (const float*)d_in[5];
  const float* Wo     = (const float*)d_in[6];
  const float* qnw    = (const float*)d_in[7];
  const float* knw    = (const float*)d_in[8];
  const int*   r_qkv  = (const int*)d_in[9];
  const int*   r_o    = (const int*)d_in[10];
  float* out = (float*)d_out;

  f16_t* xq   = (f16_t*)d_ws;                                    // [2048][4096] f16
  f16_t* wcat = xq + (size_t)M_ROWS * HID;                       // [6144][4096] f16
  f16_t* woq  = wcat + (size_t)NQKV * HID;                       // [4096][4096] f16
  f16_t* qkv  = woq + (size_t)HID * HID;                         // [2048][6144] f16
  f16_t* Qb   = qkv + (size_t)M_ROWS * NQKV;                     // [2*32*1024][128] f16
  f16_t* Kb   = Qb + (size_t)2 * NH * S_LEN * HD;                // [2*8*1024][128] f16
  f16_t* Vt   = Kb + (size_t)2 * NKV * S_LEN * HD;               // [2*8][128][1024] f16
  f16_t* ao   = Vt + (size_t)2 * NKV * S_LEN * HD;               // [2048][4096] f16
  float* sa1  = (float*)(ao + (size_t)M_ROWS * HID);             // [2048] f32
  float* sa2  = sa1 + M_ROWS;                                    // [2048] f32
  size_t needed = (size_t)((char*)(sa2 + M_ROWS) - (char*)d_ws);
  if (ws_size < needed) return;
  f16_t* oq = xq;      // alias: quantized attn output (xq dead after QKV GEMM)

  // all preprocessing (4 weight quants + activation quant) in one launch
  prep_all<<<NQKV + HID + M_ROWS, 256, 0, stream>>>(Wq, Wk, Wv, Wo, hidden,
                                                    r_qkv, r_o, wcat, woq, xq, sa1);
  // QKV: 128x192 tiles (LDS 80KB -> 2 blocks/CU), waves 2Mx4N, grid 32x16 = 512
  gemm_bt<128, 192, 2, f16_t><<<dim3(NQKV / 192, M_ROWS / 128), 512, 0, stream>>>(xq, wcat, qkv, sa1, NQKV, HID);
  post_kernel<<<M_ROWS, 512, 0, stream>>>(qkv, cosb, sinb, qnw, knw, Qb, Kb);
  vtrans_kernel<<<2 * NKV * 8, 256, 0, stream>>>(qkv, Vt);
  attn_mfma<<<512, 512, 0, stream>>>(Qb, Kb, Vt, ao);
  aquant16_kernel<<<M_ROWS, 256, 0, stream>>>(ao, r_o, oq, sa2);
  // O-proj: 128x128 tiles (LDS 64KB -> 2 blocks/CU), waves 2Mx4N, grid 32x16 = 512
  gemm_bt<128, 128, 2, float><<<dim3(HID / 128, M_ROWS / 128), 512, 0, stream>>>(oq, woq, out, sa2, HID, HID);
}